// Round 7
// baseline (368.141 us; speedup 1.0000x reference)
//
#include <hip/hip_runtime.h>
#include <stdint.h>
#include <math.h>

#define WAVE 64
#define TOPK 16
#define NBLK 1024  // == 4 blocks/CU (launch_bounds cap) * 256 CUs: all resident

// Monotone bijection fp32 -> uint32 (order-preserving).
__device__ __forceinline__ uint32_t f2s(float f) {
    uint32_t u = __float_as_uint(f);
    return u ^ (uint32_t)(((int32_t)u >> 31) | 0x80000000u);
}
__device__ __forceinline__ uint32_t umax32(uint32_t a, uint32_t b) { return a > b ? a : b; }
__device__ __forceinline__ uint32_t umin32(uint32_t a, uint32_t b) { return a < b ? a : b; }

template <int CTRL, int RMASK>
__device__ __forceinline__ uint32_t dppmax(uint32_t m) {
    uint32_t r = (uint32_t)__builtin_amdgcn_update_dpp((int)m, (int)m, CTRL, RMASK, 0xF, false);
    return umax32(m, r);
}

// Wave-wide (64-lane) max, pure VALU (DPP) + one readlane. Returns uniform value.
__device__ __forceinline__ uint32_t wave_umax(uint32_t m) {
    m = dppmax<0x121, 0xF>(m);  // row_ror:1
    m = dppmax<0x122, 0xF>(m);  // row_ror:2
    m = dppmax<0x124, 0xF>(m);  // row_ror:4
    m = dppmax<0x128, 0xF>(m);  // row_ror:8  -> row max everywhere
    m = dppmax<0x142, 0xA>(m);  // row_bcast:15 -> rows 1,3
    m = dppmax<0x143, 0xC>(m);  // row_bcast:31 -> rows 2,3; lane 63 = global
    return (uint32_t)__builtin_amdgcn_readlane((int)m, 63);
}

// global position from (local slot j, lane) -- matches the load layout
template <int VPL>
__device__ __forceinline__ uint32_t gpos(int j, int lane) {
    if constexpr (VPL == 1) return (uint32_t)lane;
    else return (uint32_t)((j >> 2) * (WAVE * 4) + lane * 4 + (j & 3));
}

// Manual grid barrier: monotonic counter (zeroed by host-side memset each call).
// All NBLK blocks are co-resident (launch_bounds-guaranteed), so spin is safe;
// bounded spin converts any residency failure into wrong-answer, not a hang.
__device__ __forceinline__ void grid_barrier(uint32_t* cnt) {
    __threadfence();   // release my stores device-wide (agent fence)
    __syncthreads();
    if (threadIdx.x == 0) {
        __hip_atomic_fetch_add(cnt, 1u, __ATOMIC_ACQ_REL, __HIP_MEMORY_SCOPE_AGENT);
        int spins = 0;
        while (__hip_atomic_load(cnt, __ATOMIC_ACQUIRE, __HIP_MEMORY_SCOPE_AGENT) < (uint32_t)NBLK) {
            __builtin_amdgcn_s_sleep(8);
            if (++spins > (1 << 21)) break;  // ~0.4s safety net
        }
    }
    __syncthreads();
    __threadfence();   // acquire side for all threads (L1/L2 inv)
}

// Per-wave top-16 weighted mean of one row (R4-validated logic).
// qkey = (f2s(v) & ~(P-1)) | global_pos -> unique total order matching stable
// argsort[-k:]. Quantized-boundary ambiguity -> exact lexicographic fallback.
template <int P>
__device__ __forceinline__ void process_row(const float* __restrict__ crow,
                                            const float* __restrict__ parent,
                                            float* __restrict__ outp,
                                            const int lane) {
    constexpr int VPL = P / WAVE;
    constexpr uint32_t IMASK = (uint32_t)(P - 1);

    uint32_t k[VPL];
    if constexpr (VPL == 1) {
        k[0] = (f2s(crow[lane]) & ~IMASK) | (uint32_t)lane;
    } else {
#pragma unroll
        for (int c = 0; c < VPL / 4; ++c) {
            float4 f4 = *reinterpret_cast<const float4*>(crow + c * (WAVE * 4) + lane * 4);
            const uint32_t b = (uint32_t)(c * (WAVE * 4) + lane * 4);
            k[c * 4 + 0] = (f2s(f4.x) & ~IMASK) | (b + 0u);
            k[c * 4 + 1] = (f2s(f4.y) & ~IMASK) | (b + 1u);
            k[c * 4 + 2] = (f2s(f4.z) & ~IMASK) | (b + 2u);
            k[c * 4 + 3] = (f2s(f4.w) & ~IMASK) | (b + 3u);
        }
        // bitonic sort, descending, key-only (all indices compile-time)
#pragma unroll
        for (int size = 2; size <= VPL; size <<= 1) {
#pragma unroll
            for (int stride = size >> 1; stride > 0; stride >>= 1) {
#pragma unroll
                for (int i = 0; i < VPL; ++i) {
                    const int j = i ^ stride;
                    if (j > i) {
                        const uint32_t a = k[i], b2 = k[j];
                        const uint32_t hi = umax32(a, b2), lo = umin32(a, b2);
                        if ((i & size) == 0) { k[i] = hi; k[j] = lo; }
                        else                 { k[i] = lo; k[j] = hi; }
                    }
                }
            }
        }
    }

    // 16 rounds: wave max of sorted heads; winner shifts its list.
    uint32_t idx[TOPK];
    uint32_t q16 = 0;
#pragma unroll
    for (int t = 0; t < TOPK; ++t) {
        const uint32_t K = wave_umax(k[0]);
        idx[t] = K & IMASK;
        if (t == TOPK - 1) q16 = K & ~IMASK;
        const bool won = (k[0] == K);   // unique keys -> exactly one lane
#pragma unroll
        for (int j = 0; j < VPL - 1; ++j) k[j] = won ? k[j + 1] : k[j];
        k[VPL - 1] = won ? 0u : k[VPL - 1];
    }
    const uint32_t k17 = wave_umax(k[0]);  // largest remaining

    // Ambiguity: only if the 17th shares the quantized prefix with the 16th.
    if ((k17 & ~IMASK) == q16) {
        // EXACT fallback (rare): lexicographic (value, index) iterative extract.
        uint32_t v[VPL];
        if constexpr (VPL == 1) {
            v[0] = f2s(crow[lane]);
        } else {
#pragma unroll
            for (int c = 0; c < VPL / 4; ++c) {
                float4 f4 = *reinterpret_cast<const float4*>(crow + c * (WAVE * 4) + lane * 4);
                v[c * 4 + 0] = f2s(f4.x);
                v[c * 4 + 1] = f2s(f4.y);
                v[c * 4 + 2] = f2s(f4.z);
                v[c * 4 + 3] = f2s(f4.w);
            }
        }
#pragma unroll
        for (int t = 0; t < TOPK; ++t) {
            uint32_t m = v[0];
            int li = 0;
#pragma unroll
            for (int j = 1; j < VPL; ++j) {
                bool c = v[j] >= m;            // ties -> higher slot (higher index)
                m = c ? v[j] : m;
                li = c ? j : li;
            }
            uint32_t gi = gpos<VPL>(li, lane);
            const uint32_t mygi = gi;
            uint32_t mm = m;
#pragma unroll
            for (int off = 32; off > 0; off >>= 1) {
                uint32_t om = (uint32_t)__shfl_xor((int)mm, off);
                uint32_t og = (uint32_t)__shfl_xor((int)gi, off);
                bool c = (om > mm) || (om == mm && og > gi);
                mm = c ? om : mm;
                gi = c ? og : gi;
            }
            idx[t] = gi;                        // uniform
            const bool won = (mygi == gi) && (m == mm);
#pragma unroll
            for (int j = 0; j < VPL; ++j) {
                if (won && j == li) v[j] = 0u;
            }
        }
    }

    // Epilogue: exact values re-read (cache-hot), softmax, weighted gather.
    float vsel[TOPK];
#pragma unroll
    for (int t = 0; t < TOPK; ++t) vsel[t] = crow[idx[t]];
    const float v0 = vsel[0];  // max (descending order / fallback extract order)
    float ssum = 0.f, acc = 0.f;
#pragma unroll
    for (int t = 0; t < TOPK; ++t) {
        const float w = __expf(vsel[t] - v0);
        ssum += w;
        acc = fmaf(w, parent[idx[t] * 64u + (uint32_t)lane], acc);
    }
    outp[lane] = acc / ssum;
}

__global__ void __launch_bounds__(256, 4)
fused_kernel(const int* __restrict__ ids,
             const float* __restrict__ conn1,
             const float* __restrict__ conn2,
             const float* __restrict__ conn3,
             const float* __restrict__ root,
             uint32_t* __restrict__ bar,   // [2] counters, zeroed each call
             float* __restrict__ e2,
             float* __restrict__ e1,
             float* __restrict__ out,
             int batch) {
    const int lane = threadIdx.x & (WAVE - 1);
    const int wib = threadIdx.x >> 6;       // wave in block (0..3)
    const int gwid = blockIdx.x * 4 + wib;  // global wave id (0..4095)

    // Phase 1: e2 (256 rows of P=64)
    if (gwid < 256) {
        process_row<64>(conn3 + gwid * 64, root, e2 + gwid * 64, lane);
    }
    grid_barrier(&bar[0]);

    // Phase 2: e1 (1024 rows of P=256) -- wave 0 of each of the 1024 blocks
    if (wib == 0) {
        process_row<256>(conn2 + (long)blockIdx.x * 256, e2, e1 + blockIdx.x * 64, lane);
    }
    grid_barrier(&bar[1]);

    // Phase 3: leaves (batch rows of P=1024), 2 rows per wave
    for (int r = gwid; r < batch; r += NBLK * 4) {
        const long src = (long)ids[r];
        process_row<1024>(conn1 + src * 1024, e1, out + (long)r * 64, lane);
    }
}

extern "C" void kernel_launch(void* const* d_in, const int* in_sizes, int n_in,
                              void* d_out, int out_size, void* d_ws, size_t ws_size,
                              hipStream_t stream) {
    const int* ids = (const int*)d_in[0];          // [8192] int32
    const float* conn1 = (const float*)d_in[1];    // [200000, 1024]
    const float* conn2 = (const float*)d_in[2];    // [1024, 256]
    const float* conn3 = (const float*)d_in[3];    // [256, 64]
    const float* root = (const float*)d_in[4];     // [64, 64]
    float* out = (float*)d_out;                    // [8192, 64]

    int batch = in_sizes[0];                       // 8192

    uint32_t* bar = (uint32_t*)d_ws;               // [2] barrier counters
    float* e2 = (float*)((char*)d_ws + 256);       // [256, 64]
    float* e1 = e2 + (size_t)256 * 64;             // [1024, 64]

    // Zero barrier counters (graph-legal async memset; deterministic per call).
    hipMemsetAsync(bar, 0, 2 * sizeof(uint32_t), stream);

    fused_kernel<<<dim3(NBLK), dim3(256), 0, stream>>>(
        ids, conn1, conn2, conn3, root, bar, e2, e1, out, batch);
}

// Round 8
// 104.268 us; speedup vs baseline: 3.5307x; 3.5307x over previous
//
#include <hip/hip_runtime.h>
#include <stdint.h>
#include <math.h>

#define WAVE 64
#define TOPK 16
#define NBLK 1024  // == 4 blocks/CU (launch_bounds cap) * 256 CUs: all resident

// Monotone bijection fp32 -> uint32 (order-preserving).
__device__ __forceinline__ uint32_t f2s(float f) {
    uint32_t u = __float_as_uint(f);
    return u ^ (uint32_t)(((int32_t)u >> 31) | 0x80000000u);
}
__device__ __forceinline__ uint32_t umax32(uint32_t a, uint32_t b) { return a > b ? a : b; }
__device__ __forceinline__ uint32_t umin32(uint32_t a, uint32_t b) { return a < b ? a : b; }

template <int CTRL, int RMASK>
__device__ __forceinline__ uint32_t dppmax(uint32_t m) {
    uint32_t r = (uint32_t)__builtin_amdgcn_update_dpp((int)m, (int)m, CTRL, RMASK, 0xF, false);
    return umax32(m, r);
}

// Wave-wide (64-lane) max, pure VALU (DPP) + one readlane. Returns uniform value.
__device__ __forceinline__ uint32_t wave_umax(uint32_t m) {
    m = dppmax<0x121, 0xF>(m);  // row_ror:1
    m = dppmax<0x122, 0xF>(m);  // row_ror:2
    m = dppmax<0x124, 0xF>(m);  // row_ror:4
    m = dppmax<0x128, 0xF>(m);  // row_ror:8  -> row max everywhere
    m = dppmax<0x142, 0xA>(m);  // row_bcast:15 -> rows 1,3
    m = dppmax<0x143, 0xC>(m);  // row_bcast:31 -> rows 2,3; lane 63 = global
    return (uint32_t)__builtin_amdgcn_readlane((int)m, 63);
}

// global position from (local slot j, lane) -- matches the load layout
template <int VPL>
__device__ __forceinline__ uint32_t gpos(int j, int lane) {
    if constexpr (VPL == 1) return (uint32_t)lane;
    else return (uint32_t)((j >> 2) * (WAVE * 4) + lane * 4 + (j & 3));
}

// Fence-free grid barrier. Counter zeroed by host-side async memset each call.
// Ordering: producers wrote e-buffers with AGENT-scope stores (visible at the
// device coherence point); the ACQ_REL arrive orders them before the count.
// Readers use normal loads: no wave reads those lines pre-barrier, dispatch
// begins L2-invalidated, and replay values are bit-identical (deterministic).
__device__ __forceinline__ void grid_barrier(uint32_t* cnt) {
    __syncthreads();
    if (threadIdx.x == 0) {
        __hip_atomic_fetch_add(cnt, 1u, __ATOMIC_ACQ_REL, __HIP_MEMORY_SCOPE_AGENT);
        int spins = 0;
        while (__hip_atomic_load(cnt, __ATOMIC_RELAXED, __HIP_MEMORY_SCOPE_AGENT) < (uint32_t)NBLK) {
            __builtin_amdgcn_s_sleep(32);            // ~0.85 us poll period
            if (++spins > (1 << 17)) break;          // ~0.1 s safety net
        }
    }
    __syncthreads();
}

// Per-wave top-16 weighted mean of one row (R4-validated logic).
// qkey = (f2s(v) & ~(P-1)) | global_pos -> unique total order matching stable
// argsort[-k:]. Quantized-boundary ambiguity -> exact lexicographic fallback.
// COH: write output through to device coherence point (for e2/e1).
template <int P, bool COH>
__device__ __forceinline__ void process_row(const float* __restrict__ crow,
                                            const float* __restrict__ parent,
                                            float* __restrict__ outp,
                                            const int lane) {
    constexpr int VPL = P / WAVE;
    constexpr uint32_t IMASK = (uint32_t)(P - 1);

    uint32_t k[VPL];
    if constexpr (VPL == 1) {
        k[0] = (f2s(crow[lane]) & ~IMASK) | (uint32_t)lane;
    } else {
#pragma unroll
        for (int c = 0; c < VPL / 4; ++c) {
            float4 f4 = *reinterpret_cast<const float4*>(crow + c * (WAVE * 4) + lane * 4);
            const uint32_t b = (uint32_t)(c * (WAVE * 4) + lane * 4);
            k[c * 4 + 0] = (f2s(f4.x) & ~IMASK) | (b + 0u);
            k[c * 4 + 1] = (f2s(f4.y) & ~IMASK) | (b + 1u);
            k[c * 4 + 2] = (f2s(f4.z) & ~IMASK) | (b + 2u);
            k[c * 4 + 3] = (f2s(f4.w) & ~IMASK) | (b + 3u);
        }
        // bitonic sort, descending, key-only (all indices compile-time)
#pragma unroll
        for (int size = 2; size <= VPL; size <<= 1) {
#pragma unroll
            for (int stride = size >> 1; stride > 0; stride >>= 1) {
#pragma unroll
                for (int i = 0; i < VPL; ++i) {
                    const int j = i ^ stride;
                    if (j > i) {
                        const uint32_t a = k[i], b2 = k[j];
                        const uint32_t hi = umax32(a, b2), lo = umin32(a, b2);
                        if ((i & size) == 0) { k[i] = hi; k[j] = lo; }
                        else                 { k[i] = lo; k[j] = hi; }
                    }
                }
            }
        }
    }

    // 16 rounds: wave max of sorted heads; winner shifts its list.
    uint32_t idx[TOPK];
    uint32_t q16 = 0;
#pragma unroll
    for (int t = 0; t < TOPK; ++t) {
        const uint32_t K = wave_umax(k[0]);
        idx[t] = K & IMASK;
        if (t == TOPK - 1) q16 = K & ~IMASK;
        const bool won = (k[0] == K);   // unique keys -> exactly one lane
#pragma unroll
        for (int j = 0; j < VPL - 1; ++j) k[j] = won ? k[j + 1] : k[j];
        k[VPL - 1] = won ? 0u : k[VPL - 1];
    }
    const uint32_t k17 = wave_umax(k[0]);  // largest remaining

    // Ambiguity: only if the 17th shares the quantized prefix with the 16th.
    if ((k17 & ~IMASK) == q16) {
        // EXACT fallback (rare): lexicographic (value, index) iterative extract.
        uint32_t v[VPL];
        if constexpr (VPL == 1) {
            v[0] = f2s(crow[lane]);
        } else {
#pragma unroll
            for (int c = 0; c < VPL / 4; ++c) {
                float4 f4 = *reinterpret_cast<const float4*>(crow + c * (WAVE * 4) + lane * 4);
                v[c * 4 + 0] = f2s(f4.x);
                v[c * 4 + 1] = f2s(f4.y);
                v[c * 4 + 2] = f2s(f4.z);
                v[c * 4 + 3] = f2s(f4.w);
            }
        }
#pragma unroll
        for (int t = 0; t < TOPK; ++t) {
            uint32_t m = v[0];
            int li = 0;
#pragma unroll
            for (int j = 1; j < VPL; ++j) {
                bool c = v[j] >= m;            // ties -> higher slot (higher index)
                m = c ? v[j] : m;
                li = c ? j : li;
            }
            uint32_t gi = gpos<VPL>(li, lane);
            const uint32_t mygi = gi;
            uint32_t mm = m;
#pragma unroll
            for (int off = 32; off > 0; off >>= 1) {
                uint32_t om = (uint32_t)__shfl_xor((int)mm, off);
                uint32_t og = (uint32_t)__shfl_xor((int)gi, off);
                bool c = (om > mm) || (om == mm && og > gi);
                mm = c ? om : mm;
                gi = c ? og : gi;
            }
            idx[t] = gi;                        // uniform
            const bool won = (mygi == gi) && (m == mm);
#pragma unroll
            for (int j = 0; j < VPL; ++j) {
                if (won && j == li) v[j] = 0u;
            }
        }
    }

    // Epilogue: exact values re-read (cache-hot), softmax, weighted gather.
    float vsel[TOPK];
#pragma unroll
    for (int t = 0; t < TOPK; ++t) vsel[t] = crow[idx[t]];
    const float v0 = vsel[0];  // max (descending order / fallback extract order)
    float ssum = 0.f, acc = 0.f;
#pragma unroll
    for (int t = 0; t < TOPK; ++t) {
        const float w = __expf(vsel[t] - v0);
        ssum += w;
        acc = fmaf(w, parent[idx[t] * 64u + (uint32_t)lane], acc);
    }
    const float r = acc / ssum;
    if constexpr (COH) {
        __hip_atomic_store(&outp[lane], r, __ATOMIC_RELAXED, __HIP_MEMORY_SCOPE_AGENT);
    } else {
        outp[lane] = r;
    }
}

__global__ void __launch_bounds__(256, 4)
fused_kernel(const int* __restrict__ ids,
             const float* __restrict__ conn1,
             const float* __restrict__ conn2,
             const float* __restrict__ conn3,
             const float* __restrict__ root,
             uint32_t* __restrict__ bar,   // [2] counters, zeroed each call
             float* __restrict__ e2,
             float* __restrict__ e1,
             float* __restrict__ out,
             int batch) {
    const int lane = threadIdx.x & (WAVE - 1);
    const int wib = threadIdx.x >> 6;       // wave in block (0..3)
    const int gwid = blockIdx.x * 4 + wib;  // global wave id (0..4095)

    // Phase 1: e2 (256 rows of P=64) -- wave 0 of blocks 0..255
    if (wib == 0 && blockIdx.x < 256) {
        process_row<64, true>(conn3 + blockIdx.x * 64, root, e2 + blockIdx.x * 64, lane);
    }
    grid_barrier(&bar[0]);

    // Phase 2: e1 (1024 rows of P=256) -- wave 0 of every block
    if (wib == 0) {
        process_row<256, true>(conn2 + (long)blockIdx.x * 256, e2, e1 + blockIdx.x * 64, lane);
    }
    grid_barrier(&bar[1]);

    // Phase 3: leaves (batch rows of P=1024), 2 rows per wave
    for (int r = gwid; r < batch; r += NBLK * 4) {
        const long src = (long)ids[r];
        process_row<1024, false>(conn1 + src * 1024, e1, out + (long)r * 64, lane);
    }
}

extern "C" void kernel_launch(void* const* d_in, const int* in_sizes, int n_in,
                              void* d_out, int out_size, void* d_ws, size_t ws_size,
                              hipStream_t stream) {
    const int* ids = (const int*)d_in[0];          // [8192] int32
    const float* conn1 = (const float*)d_in[1];    // [200000, 1024]
    const float* conn2 = (const float*)d_in[2];    // [1024, 256]
    const float* conn3 = (const float*)d_in[3];    // [256, 64]
    const float* root = (const float*)d_in[4];     // [64, 64]
    float* out = (float*)d_out;                    // [8192, 64]

    int batch = in_sizes[0];                       // 8192

    uint32_t* bar = (uint32_t*)d_ws;               // [2] barrier counters
    float* e2 = (float*)((char*)d_ws + 256);       // [256, 64]
    float* e1 = e2 + (size_t)256 * 64;             // [1024, 64]

    // Zero barrier counters (graph-legal async memset; deterministic per call).
    hipMemsetAsync(bar, 0, 2 * sizeof(uint32_t), stream);

    fused_kernel<<<dim3(NBLK), dim3(256), 0, stream>>>(
        ids, conn1, conn2, conn3, root, bar, e2, e1, out, batch);
}